// Round 4
// baseline (141.242 us; speedup 1.0000x reference)
//
#include <hip/hip_runtime.h>
#include <math.h>

namespace {

constexpr int W_TS = 256, NE = 16, NB = 512, NI = 10, NF = 3;
constexpr int BI   = NB * NI;          // 5120
constexpr int PROJ = 7, IN_P = 4, EMB = 32, NTOT = 79;
constexpr int BLK  = 64;               // 1 wave/block -> 1280 blocks = 5 blocks/CU, balanced
constexpr int PFK  = 32;               // prefetch depth: 32 x ~30cyc issue ≈ 1000cyc ≈ HBM latency
constexpr float MAX_RATIO    = 0.5f;
constexpr float INV_SQRT_DEG = 0.70710678118654752440f;
constexpr size_t TS_IN  = (size_t)NE * BI * NF;   // floats per timestep (input)
constexpr size_t TS_OUT = (size_t)NE * BI;        // floats per timestep (output)

__device__ __forceinline__ float gelu_exact(float x) {
  return 0.5f * x * (1.0f + erff(x * 0.70710678118654752440f));
}

template<int N, int OB>
__device__ __forceinline__ void constrain_group(
    const float* __restrict__ Wo, const float* __restrict__ bo,
    const float* __restrict__ h1, const float* __restrict__ refw,
    float* __restrict__ outw)
{
  float off[N];
  float ss = 0.f;
#pragma unroll
  for (int n = 0; n < N; ++n) {
    float acc = bo[OB + n];
#pragma unroll
    for (int i = 0; i < EMB; ++i)
      acc = fmaf(Wo[(OB + n) * EMB + i], h1[i], acc);
    off[n] = acc;
    ss = fmaf(acc, acc, ss);
  }
  float rn = 0.f;
#pragma unroll
  for (int n = 0; n < N; ++n) { float w = refw[n]; rn = fmaf(w, w, rn); }
  float max_norm = fmaxf(sqrtf(rn) * MAX_RATIO, 0.01f);
  float scale    = fminf(max_norm / (sqrtf(ss) + 1e-8f), 1.0f);
#pragma unroll
  for (int n = 0; n < N; ++n) outw[n] = refw[n] + off[n] * scale;
}

__global__ __launch_bounds__(BLK)
void ensemble_rnn(const float* __restrict__ xin,       // (W_TS,E,BI,F)
                  const float* __restrict__ h0,        // (E,BI)
                  const float* __restrict__ embedding, // (E,NB,EMB)
                  const float* __restrict__ w0g,       // (E,7,4)
                  const float* __restrict__ w1g,       // (E,7,4)
                  const float* __restrict__ b0g,       // (E,7)
                  const float* __restrict__ b1g,       // (E,7)
                  const float* __restrict__ wng,       // (E,1,7)
                  const float* __restrict__ bng,       // (E,1)
                  const float* __restrict__ damping,   // (E)
                  const float* __restrict__ hW_in,     // (E,32,32)
                  const float* __restrict__ hb_in,     // (E,32)
                  const float* __restrict__ hW_out,    // (E,79,32)
                  const float* __restrict__ hb_out,    // (E,79)
                  float* __restrict__ out)             // (W_TS,E,BI)
{
  constexpr int BLOCKS_PER_E = BI / BLK;  // 80 -> e block-uniform
  const int e  = (int)blockIdx.x / BLOCKS_PER_E;
  const int cg = (int)blockIdx.x * BLK + (int)threadIdx.x;  // = e*BI + bi
  const int bi = cg - e * BI;
  const int b  = bi / NI;

  // ---------------- hypernetwork (once per thread) ----------------
  float emb[EMB];
  {
    const float4* ep =
        reinterpret_cast<const float4*>(embedding + ((size_t)e * NB + b) * EMB);
#pragma unroll
    for (int i = 0; i < EMB / 4; ++i) {
      float4 v = ep[i];
      emb[4*i+0] = v.x; emb[4*i+1] = v.y; emb[4*i+2] = v.z; emb[4*i+3] = v.w;
    }
  }
  float h1[EMB];
  {
    const float* Wi = hW_in + (size_t)e * EMB * EMB;
    const float* bb = hb_in + (size_t)e * EMB;
#pragma unroll
    for (int o = 0; o < EMB; ++o) {
      float acc = bb[o];
#pragma unroll
      for (int i = 0; i < EMB; ++i) acc = fmaf(Wi[o * EMB + i], emb[i], acc);
      h1[o] = gelu_exact(acc);
    }
  }
  const float* Wo = hW_out + (size_t)e * NTOT * EMB;
  const float* bo = hb_out + (size_t)e * NTOT;

  float w0e[PROJ * IN_P], w1e[PROJ * IN_P];
  float b0e[PROJ], b1e[PROJ], wns[PROJ], bne;

  constrain_group<28, 0 >(Wo, bo, h1, w0g + e * 28, w0e);
  constrain_group<28, 28>(Wo, bo, h1, w1g + e * 28, w1e);
  constrain_group<7,  56>(Wo, bo, h1, b0g + e * 7,  b0e);
  constrain_group<7,  63>(Wo, bo, h1, b1g + e * 7,  b1e);
  constrain_group<7,  70>(Wo, bo, h1, wng + e * 7,  wns);
  constrain_group<1,  77>(Wo, bo, h1, bng + e,      &bne);

  const float dec = 1.0f / (1.0f + expf(-damping[e]));
  const float omd = 1.0f - dec;

  // ---------------- collapse to 5x5 quadratic form --------------------------
  float M[5][5];
#pragma unroll
  for (int i = 0; i < 5; ++i)
#pragma unroll
    for (int j = 0; j < 5; ++j) M[i][j] = 0.f;

#pragma unroll
  for (int o = 0; o < PROJ; ++o) {
    const float s = wns[o] * INV_SQRT_DEG;
    float w0h[5] = { w0e[o*4+0], w0e[o*4+1], w0e[o*4+2], w0e[o*4+3], b0e[o] };
    float w1h[5] = { w1e[o*4+0], w1e[o*4+1], w1e[o*4+2], w1e[o*4+3], b1e[o] };
#pragma unroll
    for (int i = 0; i < 5; ++i) {
      const float t = s * w0h[i];
#pragma unroll
      for (int j = 0; j < 5; ++j) M[i][j] = fmaf(t, w1h[j], M[i][j]);
    }
  }
  const float c00 = M[0][0];
  const float c01 = M[0][1] + M[1][0];
  const float c02 = M[0][2] + M[2][0];
  const float c03 = M[0][3] + M[3][0];
  const float c04 = M[0][4] + M[4][0];
  const float c11 = M[1][1];
  const float c12 = M[1][2] + M[2][1];
  const float c13 = M[1][3] + M[3][1];
  const float c14 = M[1][4] + M[4][1];
  const float c22 = M[2][2];
  const float c23 = M[2][3] + M[3][2];
  const float c24 = M[2][4] + M[4][2];
  const float c33 = M[3][3];
  const float c34 = M[3][4] + M[4][3] + omd;   // leak folded in
  const float c44 = M[4][4] + bne;             // bias folded in

  // ---------------- RNN scan (hot loop) ----------------
  float h = h0[cg];
  const float* xbase = xin + (size_t)cg * NF;
  float* obase = out + cg;

  float xb[PFK][3];
#pragma unroll
  for (int k = 0; k < PFK; ++k) {
    const float* p = xbase + (size_t)k * TS_IN;
    xb[k][0] = p[0]; xb[k][1] = p[1]; xb[k][2] = p[2];   // merges to dwordx3
  }

#define STEP(T, K, DO_PF)                                          \
  do {                                                             \
    const float x0 = xb[K][0], x1 = xb[K][1], x2 = xb[K][2];       \
    if (DO_PF) {                                                   \
      const float* p = xbase + (size_t)((T) + PFK) * TS_IN;        \
      xb[K][0] = p[0]; xb[K][1] = p[1]; xb[K][2] = p[2];           \
    }                                                              \
    float r0 = fmaf(c00, x0, c04);                                 \
    r0 = fmaf(c01, x1, r0); r0 = fmaf(c02, x2, r0);                \
    r0 = fmaf(c03, h, r0);                                         \
    float r1 = fmaf(c11, x1, c14);                                 \
    r1 = fmaf(c12, x2, r1); r1 = fmaf(c13, h, r1);                 \
    float r2 = fmaf(c22, x2, c24); r2 = fmaf(c23, h, r2);          \
    float r3 = fmaf(c33, h, c34);                                  \
    float hn = c44;                                                \
    hn = fmaf(x0, r0, hn); hn = fmaf(x1, r1, hn);                  \
    hn = fmaf(x2, r2, hn); hn = fmaf(h, r3, hn);                   \
    h = hn;                                                        \
    __builtin_nontemporal_store(h, &obase[(size_t)(T) * TS_OUT]);  \
  } while (0)

  int tc = 0;
  for (; tc < W_TS - PFK; tc += PFK) {
#pragma unroll
    for (int k = 0; k < PFK; ++k) STEP(tc + k, k, true);
  }
#pragma unroll
  for (int k = 0; k < PFK; ++k) STEP(tc + k, k, false);
#undef STEP
}

} // anonymous namespace

extern "C" void kernel_launch(void* const* d_in, const int* in_sizes, int n_in,
                              void* d_out, int out_size, void* d_ws, size_t ws_size,
                              hipStream_t stream) {
  const float* xin  = (const float*)d_in[0];
  const float* h0   = (const float*)d_in[1];
  const float* emb  = (const float*)d_in[2];
  const float* w0   = (const float*)d_in[3];
  const float* w1   = (const float*)d_in[4];
  const float* b0   = (const float*)d_in[5];
  const float* b1   = (const float*)d_in[6];
  const float* wn   = (const float*)d_in[7];
  const float* bn   = (const float*)d_in[8];
  const float* damp = (const float*)d_in[9];
  const float* hWi  = (const float*)d_in[10];
  const float* hbi  = (const float*)d_in[11];
  const float* hWo  = (const float*)d_in[12];
  const float* hbo  = (const float*)d_in[13];
  float* out = (float*)d_out;

  dim3 grid(NE * BI / BLK);   // 1280 blocks
  dim3 block(BLK);            // 64 threads = 1 wave
  hipLaunchKernelGGL(ensemble_rnn, grid, block, 0, stream,
                     xin, h0, emb, w0, w1, b0, b1, wn, bn, damp,
                     hWi, hbi, hWo, hbo, out);
}